// Round 3
// baseline (263.672 us; speedup 1.0000x reference)
//
#include <hip/hip_runtime.h>
#include <hip/hip_bf16.h>
#include <math.h>

#define N_BATCH 8
#define WDIM 64
#define TDIM 8192
#define KBINS 2048
#define NROWS (N_BATCH * TDIM)          // 65536
#define XSIZE (N_BATCH * WDIM * TDIM)   // 4194304
#define XL_OFF 0
#define XD_OFF NROWS
#define SCAL_OFF (NROWS + XSIZE)

#define MT 64                           // rows per block (vq); 512 thr = 8 waves = 2 teams x 4
#define XST 72                          // bf16 LDS x row stride
#define TAU 0.05f                       // >=16x split-bf16 vs np noise
#define MAXFLAG 8192
#define NBLK (NROWS / MT)               // 1024

// ws layout (bytes):
//   0      : float k2[KBINS]            (8192)
//   8192   : int   flag_cnt             (pad to 64)
//   8256   : int   flags[MAXFLAG]       (32768)
//   41024  : u64   slots[MAXFLAG]       (65536)
//   106560 : float part[4][NBLK]        (16384)
//   122944 : char  kfrag[128 tiles * 4096]  (524288)
//   647296 : float kT[64][2048]         (524288, optional if ws_size permits)
#define WS_K2_OFF   0
#define WS_CNT_OFF  8192
#define WS_FLAG_OFF 8256
#define WS_SLOT_OFF 41024
#define WS_PART_OFF 106560
#define WS_KF_OFF   122944
#define WS_KT_OFF   647296
#define WS_KT_END   (WS_KT_OFF + (size_t)WDIM * KBINS * 4)

typedef __attribute__((ext_vector_type(8))) short bf16x8;
typedef __attribute__((ext_vector_type(4))) float f32x4;
typedef unsigned long long u64;

static __device__ __forceinline__ short f2bf(float v) {
  __hip_bfloat16 b = __float2bfloat16(v);
  return *reinterpret_cast<short*>(&b);
}
static __device__ __forceinline__ float bf2f(short s) {
  unsigned int u = ((unsigned int)(unsigned short)s) << 16;
  return __uint_as_float(u);
}

#define GLOAD_LDS(gsrc, ldst)                                            \
  __builtin_amdgcn_global_load_lds(                                      \
      (const __attribute__((address_space(1))) unsigned int*)(gsrc),     \
      (__attribute__((address_space(3))) unsigned int*)(ldst), 16, 0, 0)

// s_waitcnt immediates (gfx9 encoding): vmcnt[3:0] | expcnt<<4 | lgkmcnt<<8
#define WAIT_VM4 0x0F74
#define WAIT_VM0 0x0F70

// raw barrier (no vmcnt drain!) + compiler memory fence
#define SBAR() asm volatile("s_barrier" ::: "memory")

// prep: 1 block per 16-code tile. np-bit-exact k2 + fragment-ordered split-bf16
// codebook + optional kT transpose + ws init (cnt, slots).
__global__ void prep_kernel(const float* __restrict__ kg, float* __restrict__ k2,
                            char* __restrict__ kfrag, float* __restrict__ kT,
                            int* __restrict__ cnt, u64* __restrict__ slots) {
  __shared__ float skc[16 * 65];
  const int tid  = threadIdx.x;
  const int tile = blockIdx.x;           // 0..127
  const int c0   = tile * 16;
  if (tile == 0 && tid == 0) *cnt = 0;
  if (tid < 64) slots[tile * 64 + tid] = ~0ULL;
  {
    const float4* g4 = (const float4*)(kg + (size_t)c0 * WDIM);
    int code = tid >> 4, w = (tid & 15) * 4;
    *(float4*)&skc[code * 65 + w] = g4[tid];
  }
  __syncthreads();
  if (tid < 16) {   // np-bit-exact k2 (8-accumulator pairwise)
    const float* kr = &skc[tid * 65];
    float r[8];
#pragma unroll
    for (int l = 0; l < 8; ++l) r[l] = __fmul_rn(kr[l], kr[l]);
    for (int i = 8; i < WDIM; i += 8) {
#pragma unroll
      for (int l = 0; l < 8; ++l)
        r[l] = __fadd_rn(r[l], __fmul_rn(kr[i + l], kr[i + l]));
    }
    k2[c0 + tid] = __fadd_rn(__fadd_rn(__fadd_rn(r[0], r[1]), __fadd_rn(r[2], r[3])),
                             __fadd_rn(__fadd_rn(r[4], r[5]), __fadd_rn(r[6], r[7])));
  }
  if (kT) {   // transposed copy for coalesced recheck reads (same values, bit-exact)
    const int code = tid & 15;
#pragma unroll
    for (int j = 0; j < 4; ++j) {
      int w = (tid >> 4) + 16 * j;
      kT[(size_t)w * KBINS + c0 + code] = skc[code * 65 + w];
    }
  }
  {
    const int sub  = tid >> 6;           // 0..3
    const int lane = tid & 63;
    const int lcol = lane & 15;
    const int quad = lane >> 4;
    const float* src = &skc[lcol * 65 + (sub & 1) * 32 + quad * 8];
    const bool lo = (sub >= 2);
    short tmp[8];
#pragma unroll
    for (int i = 0; i < 8; ++i) {
      float v = src[i];
      short h = f2bf(v);
      tmp[i] = lo ? f2bf(v - bf2f(h)) : h;
    }
    char* dst = kfrag + (size_t)tile * 4096 + sub * 1024 + lane * 16;
    *(bf16x8*)dst = *(const bf16x8*)tmp;
  }
}

// main: split-bf16 MFMA scan, CODE-SPLIT across two 4-wave teams.
// 512 thr = 8 waves; team = wave>>2. Team 0 scans code tiles 0..63, team 1
// tiles 64..127, SAME 64 rows. Each team: private 3-slot shared ring filled
// by its wave (wave&3)==0 via async global_load_lds behind per-wave vmcnt
// literals; one raw s_barrier per step (no vmcnt drain). Epilogue merges the
// two teams' argmin via LDS (strict < : team-0 codes are lower -> exact
// lowest-index tie-break preserved).
// Occupancy: 8192 waves total; VGPR forced <=64 via launch_bounds(512,8);
// LDS = 2x12288 ring + 8192 k2f + smalls = 34184 -> 4 blocks/CU = 32 waves/CU.
__launch_bounds__(512, 8)
__global__ void vq_mfma(const float* __restrict__ x,
                        const float* __restrict__ kg,
                        const float* __restrict__ k2g,
                        const char* __restrict__ kfrag,
                        float* __restrict__ out,
                        float* __restrict__ part,
                        int* __restrict__ flag_cnt,
                        int* __restrict__ flags) {
  __shared__ __align__(16) char smem[34184];
  // persistent through the scan loop:
  char*  kbuf = smem;                      // 2 teams x 3 x 4096 rings (24576)
  float* k2f  = (float*)(smem + 24576);    // k2[2048]                 (8192)
  // dedicated smalls (live across loop/epilogue):
  float* mbd       = (float*)(smem + 32768);  // 64 merge bd
  float* mb2       = (float*)(smem + 33024);  // 64 merge b2
  int*   mbi       = (int*)  (smem + 33280);  // 64 merge bi
  int*   sIdx      = (int*)  (smem + 33536);  // 64 ints
  float* sPair     = (float*)(smem + 33792);  // 32 floats wave sums
  int*   sFlagCnt  = (int*)  (smem + 33920);
  int*   sFlagBase = (int*)  (smem + 33924);
  int*   sFlagList = (int*)  (smem + 33928);  // 64 ints (ends 34184)
  // prologue overlay of rings (dead before first ring write, barrier-protected):
  short* sxh = (short*)smem;               // [64][72] bf16 hi     (9216)
  short* sxl = (short*)(smem + 9216);      // [64][72] bf16 lo     (9216, ends 18432)
  // epilogue overlay of rings:
  float* kd  = (float*)smem;               // [64][68] f32         (17408)

  const int tid  = threadIdx.x;
  const int blk  = blockIdx.x;
  const int row0 = blk * MT;
  const int n    = row0 >> 13;
  const int t0   = row0 & (TDIM - 1);

  // ---- stage x tile -> split bf16; k2 -> LDS; fp32 partials in regs ----
  const int r  = tid & 63;
  const int wh = tid >> 6;                 // 0..7
  float x2p = 0.f, sxp = 0.f;
  const float* xb = x + (size_t)n * WDIM * TDIM + t0 + r;
#pragma unroll
  for (int i = 0; i < 8; ++i) {
    int w = 8 * i + wh;
    float v = xb[(size_t)w * TDIM];
    x2p = fmaf(v, v, x2p);
    sxp += v;
    short h = f2bf(v);
    sxh[r * XST + w] = h;
    sxl[r * XST + w] = f2bf(v - bf2f(h));
  }
  {   // k2f region (24576..32768) is disjoint from sxh/sxl: stage now
    const float4* k24 = (const float4*)k2g;
    *(float4*)&k2f[tid * 4] = k24[tid];
  }
  __syncthreads();

  // ---- A fragments (each wave: one 16-row subtile, g = wave&3) ----
  const int wave = tid >> 6;
  const int lane = tid & 63;
  const int lcol = lane & 15;
  const int quad = lane >> 4;
  const int team = wave >> 2;              // 0 or 1
  const int g    = wave & 3;               // row-group
  const bool iw  = (g == 0);               // issuer wave of this team
  const int rA = g * 16 + lcol;
  bf16x8 ah0 = *(const bf16x8*)&sxh[rA * XST + 0  + quad * 8];
  bf16x8 ah1 = *(const bf16x8*)&sxh[rA * XST + 32 + quad * 8];
  bf16x8 al0 = *(const bf16x8*)&sxl[rA * XST + 0  + quad * 8];
  bf16x8 al1 = *(const bf16x8*)&sxl[rA * XST + 32 + quad * 8];
  // sxh/sxl must be fully consumed (all waves) before ring writes land.
  __syncthreads();

  float bd[4], b2[4];
  int   bi[4];
#pragma unroll
  for (int i = 0; i < 4; ++i) { bd[i] = 3.0e38f; b2[i] = 3.0e38f; bi[i] = 0; }

  const char* kfg = kfrag;
  char* myring = kbuf + team * 12288;      // this team's 3 x 4096 ring
  const int Tb = team * 64;                // first global tile of this team

  // issue async stage of global tile CG into this team's ring slot B
#define VQ_ISSUE(CG, B)                                                      \
  {                                                                          \
    const char* s = kfg + (size_t)(CG) * 4096 + (lane << 4);                 \
    char* d = myring + (B) * 4096;                                           \
    GLOAD_LDS(s, d);                                                         \
    GLOAD_LDS(s + 1024, d + 1024);                                           \
    GLOAD_LDS(s + 2048, d + 2048);                                           \
    GLOAD_LDS(s + 3072, d + 3072);                                           \
  }

  // prologue: each team's issuer primes 2 tiles (k2f/A-frags already done)
  if (iw) {
    VQ_ISSUE(Tb + 0, 0)
    VQ_ISSUE(Tb + 1, 1)
  }

  // one 16-code step (CR = team-relative tile): issuer waits ring slot RB,
  // barrier, all consume, issuer prefetches CR+2 into PB (if DOISS).
#define VQ_STEP(CR, RB, PB, WAITIMM, DOISS)                                  \
  {                                                                          \
    if (iw) __builtin_amdgcn_s_waitcnt(WAITIMM);                             \
    SBAR();                                                                  \
    const char* tb = myring + (RB) * 4096;                                   \
    bf16x8 bh0 = *(const bf16x8*)(tb + 0    + (lane << 4));                  \
    bf16x8 bh1 = *(const bf16x8*)(tb + 1024 + (lane << 4));                  \
    bf16x8 bl0 = *(const bf16x8*)(tb + 2048 + (lane << 4));                  \
    bf16x8 bl1 = *(const bf16x8*)(tb + 3072 + (lane << 4));                  \
    const int cg = Tb + (CR);                                                \
    float k2c = k2f[cg * 16 + lcol];                                         \
    if (iw && (DOISS)) { VQ_ISSUE(cg + 2, PB) }                              \
    f32x4 p = {0.f, 0.f, 0.f, 0.f};                                          \
    p = __builtin_amdgcn_mfma_f32_16x16x32_bf16(ah0, bh0, p, 0, 0, 0);       \
    p = __builtin_amdgcn_mfma_f32_16x16x32_bf16(ah1, bh1, p, 0, 0, 0);       \
    p = __builtin_amdgcn_mfma_f32_16x16x32_bf16(ah0, bl0, p, 0, 0, 0);       \
    p = __builtin_amdgcn_mfma_f32_16x16x32_bf16(ah1, bl1, p, 0, 0, 0);       \
    p = __builtin_amdgcn_mfma_f32_16x16x32_bf16(al0, bh0, p, 0, 0, 0);       \
    p = __builtin_amdgcn_mfma_f32_16x16x32_bf16(al1, bh1, p, 0, 0, 0);       \
    const int code = cg * 16 + lcol;                                         \
    _Pragma("unroll")                                                        \
    for (int i = 0; i < 4; ++i) {                                            \
      float d0 = fmaf(-2.f, p[i], k2c);                                      \
      float nb2 = __builtin_amdgcn_fmed3f(bd[i], d0, b2[i]);                 \
      bool lt0 = d0 < bd[i];                                                 \
      bd[i] = lt0 ? d0 : bd[i];                                              \
      bi[i] = lt0 ? code : bi[i];                                            \
      b2[i] = nb2;                                                           \
    }                                                                        \
  }

  for (int c = 0; c < 60; c += 3) {
    VQ_STEP(c,     0, 2, WAIT_VM4, 1)
    VQ_STEP(c + 1, 1, 0, WAIT_VM4, 1)
    VQ_STEP(c + 2, 2, 1, WAIT_VM4, 1)
  }
  VQ_STEP(60, 0, 2, WAIT_VM4, 1)
  VQ_STEP(61, 1, 0, WAIT_VM4, 1)
  VQ_STEP(62, 2, 1, WAIT_VM4, 0)
  VQ_STEP(63, 0, 2, WAIT_VM0, 0)
#undef VQ_STEP
#undef VQ_ISSUE

  // ---- reduce across the 16 col-classes (registers only, within-team) ----
#pragma unroll
  for (int m = 1; m < 16; m <<= 1) {
#pragma unroll
    for (int i = 0; i < 4; ++i) {
      float od  = __shfl_xor(bd[i], m, 64);
      float od2 = __shfl_xor(b2[i], m, 64);
      int   oi  = __shfl_xor(bi[i], m, 64);
      float nb2 = fminf(fminf(b2[i], od2), fmaxf(bd[i], od));
      bool take = (od < bd[i]) || (od == bd[i] && oi < bi[i]);
      bd[i] = take ? od : bd[i];
      bi[i] = take ? oi : bi[i];
      b2[i] = nb2;
    }
  }

  __syncthreads();                 // loop LDS regions now dead for all waves
  if (tid == 0) *sFlagCnt = 0;
  // team 1 publishes its per-row results for the cross-team merge
  if (team == 1 && lcol == 0) {
#pragma unroll
    for (int i = 0; i < 4; ++i) {
      int rloc = g * 16 + quad * 4 + i;
      mbd[rloc] = bd[i];
      mb2[rloc] = b2[i];
      mbi[rloc] = bi[i];
    }
  }
  __syncthreads();

  float fit_p = 0.f;   // sum of (k2 - 2*dot) minima; row x2 added via v1 fold
  if (team == 0 && lcol == 0) {
#pragma unroll
    for (int i = 0; i < 4; ++i) {
      int rloc = g * 16 + quad * 4 + i;
      int rowg = row0 + rloc;
      // merge team 1 (strict <: team-0 codes are lower-index on ties)
      float obd = mbd[rloc], ob2 = mb2[rloc];
      int   obi = mbi[rloc];
      float nb2 = fminf(fminf(b2[i], ob2), fmaxf(bd[i], obd));
      bool take = obd < bd[i];
      float fbd = take ? obd : bd[i];
      int   fbi = take ? obi : bi[i];
      out[XL_OFF + rowg] = (float)fbi;
      sIdx[rloc] = fbi;
      fit_p += fbd;
      if (nb2 - fbd < TAU) {
        int slot = atomicAdd(sFlagCnt, 1);   // LDS atomic (cheap)
        sFlagList[slot] = rowg;
      }
    }
  }
  __syncthreads();

  // one global atomic per block for the flag range
  int nloc = *sFlagCnt;
  if (tid == 0 && nloc > 0) *sFlagBase = atomicAdd(flag_cnt, nloc);
  __syncthreads();
  if (tid < nloc) {
    int gs = *sFlagBase + tid;
    if (gs < MAXFLAG) flags[gs] = sFlagList[tid];
  }

  // ---- gather chosen code rows (fp32) into LDS (ring overlay, now dead) ----
  {
    int rr = tid >> 3, q8 = tid & 7;
    const float4* kr4 = (const float4*)(kg + (size_t)sIdx[rr] * WDIM) + q8 * 2;
    float4* dst = (float4*)&kd[rr * 68 + q8 * 8];
    dst[0] = kr4[0];
    dst[1] = kr4[1];
  }
  __syncthreads();

  // ---- x_d transposed write + commit ----
  float commit_p = 0.f;
  float* xdb = out + XD_OFF + (size_t)n * WDIM * TDIM + t0 + r;
#pragma unroll
  for (int i = 0; i < 8; ++i) {
    int w = 8 * i + wh;
    float xvv = xb[(size_t)w * TDIM];
    float kvv = kd[r * 68 + w];
    float df = kvv - xvv;
    commit_p = fmaf(df, df, commit_p);
    xdb[(size_t)w * TDIM] = kvv;
  }

  // ---- block scalar partials -> per-block arrays (no atomics) ----
  float v0 = sxp, v1 = x2p, v2 = commit_p, v3 = fit_p;
#pragma unroll
  for (int off = 32; off > 0; off >>= 1) {
    v0 += __shfl_down(v0, off, 64);
    v1 += __shfl_down(v1, off, 64);
    v2 += __shfl_down(v2, off, 64);
    v3 += __shfl_down(v3, off, 64);
  }
  if (lane == 0) {
    sPair[wave * 4 + 0] = v0;
    sPair[wave * 4 + 1] = v1;
    sPair[wave * 4 + 2] = v2;
    sPair[wave * 4 + 3] = v3;
  }
  __syncthreads();
  if (tid == 0) {
    float s0 = 0.f, s1 = 0.f, s2 = 0.f, s3 = 0.f;
#pragma unroll
    for (int w8 = 0; w8 < 8; ++w8) {
      s0 += sPair[w8 * 4 + 0];
      s1 += sPair[w8 * 4 + 1];
      s2 += sPair[w8 * 4 + 2];
      s3 += sPair[w8 * 4 + 3];
    }
    part[0 * NBLK + blk] = s0;
    part[1 * NBLK + blk] = s1;
    part[2 * NBLK + blk] = s2;
    part[3 * NBLK + blk] = s3 + s1;   // fit row = bd + x2
  }
}

// recheck pass 1: persistent grid; item = (flagged row, 256-code segment).
// kT (transposed codebook) gives lane-coalesced k reads; identical fmaf chain
// order as the kg-row path -> bit-identical distances.
__launch_bounds__(256, 4)
__global__ void recheck_scan(const float* __restrict__ x,
                             const float* __restrict__ kg,
                             const float* __restrict__ kT,
                             const float* __restrict__ k2g,
                             const int* __restrict__ flag_cnt,
                             const int* __restrict__ flags,
                             u64* __restrict__ slots) {
  __shared__ float sx[WDIM];
  __shared__ float sx2s;
  const int tid = threadIdx.x;
  int nf = *flag_cnt;
  if (nf > MAXFLAG) nf = MAXFLAG;
  const int total = nf * 8;

  for (int g = blockIdx.x; g < total; g += 2048) {
    const int fi  = g >> 3;
    const int seg = g & 7;
    const int row = flags[fi];
    const int n = row >> 13;
    const int t = row & (TDIM - 1);
    if (tid < WDIM) sx[tid] = x[(size_t)n * WDIM * TDIM + (size_t)tid * TDIM + t];
    __syncthreads();
    if (tid == 0) {   // np-pairwise x2
      float r8[8];
#pragma unroll
      for (int l = 0; l < 8; ++l) r8[l] = __fmul_rn(sx[l], sx[l]);
      for (int i = 8; i < WDIM; i += 8) {
#pragma unroll
        for (int l = 0; l < 8; ++l)
          r8[l] = __fadd_rn(r8[l], __fmul_rn(sx[i + l], sx[i + l]));
      }
      sx2s = __fadd_rn(__fadd_rn(__fadd_rn(r8[0], r8[1]), __fadd_rn(r8[2], r8[3])),
                       __fadd_rn(__fadd_rn(r8[4], r8[5]), __fadd_rn(r8[6], r8[7])));
    }
    __syncthreads();

    const int j = seg * 256 + tid;
    float c = 0.f;
    if (kT) {
#pragma unroll
      for (int w = 0; w < WDIM; ++w)
        c = __fmaf_rn(sx[w], kT[(size_t)w * KBINS + j], c);
    } else {
      const float* kr = kg + (size_t)j * WDIM;
#pragma unroll
      for (int w = 0; w < WDIM; ++w)
        c = __fmaf_rn(sx[w], kr[w], c);
    }
    float d = __fadd_rn(__fsub_rn(sx2s, __fmul_rn(2.0f, c)), k2g[j]);

    u64 key = ((u64)__float_as_uint(d) << 32) | (unsigned int)j;
#pragma unroll
    for (int off = 32; off > 0; off >>= 1) {
      u64 o = __shfl_down((unsigned long long)key, off, 64);
      if (o < key) key = o;
    }
    if ((tid & 63) == 0) atomicMin(&slots[fi], key);
    __syncthreads();
  }
}

// recheck pass 2: persistent write-back.
__global__ void recheck_write(const float* __restrict__ kg,
                              const int* __restrict__ flag_cnt,
                              const int* __restrict__ flags,
                              const u64* __restrict__ slots,
                              float* __restrict__ out) {
  int nf = *flag_cnt;
  if (nf > MAXFLAG) nf = MAXFLAG;
  const int w = threadIdx.x;
  for (int fi = blockIdx.x; fi < nf; fi += 256) {
    const int row = flags[fi];
    const int n = row >> 13;
    const int t = row & (TDIM - 1);
    const int j = (int)(slots[fi] & 0xFFFFFFFFULL);
    if (w == 0) out[XL_OFF + row] = (float)j;
    out[XD_OFF + (size_t)n * WDIM * TDIM + (size_t)w * TDIM + t] = kg[(size_t)j * WDIM + w];
  }
}

// finalize: sum per-block partials (fp64) + emit the 3 scalars.
__global__ void finalize_kernel(const float* __restrict__ part, float* __restrict__ out) {
  __shared__ double sred[4][64];
  const int tid = threadIdx.x;     // 256
  const int lane = tid & 63;
  const int wv = tid >> 6;
  double a[4] = {0.0, 0.0, 0.0, 0.0};
  for (int i = tid; i < NBLK; i += 256) {
#pragma unroll
    for (int q = 0; q < 4; ++q) a[q] += (double)part[q * NBLK + i];
  }
#pragma unroll
  for (int off = 32; off > 0; off >>= 1) {
#pragma unroll
    for (int q = 0; q < 4; ++q)
      a[q] += __shfl_down(a[q], off, 64);
  }
  if (lane == 0) {
#pragma unroll
    for (int q = 0; q < 4; ++q) sred[q][wv] = a[q];
  }
  __syncthreads();
  if (tid == 0) {
    double s0 = 0, s1 = 0, s2 = 0, s3 = 0;
#pragma unroll
    for (int wv2 = 0; wv2 < 4; ++wv2) {
      s0 += sred[0][wv2]; s1 += sred[1][wv2];
      s2 += sred[2][wv2]; s3 += sred[3][wv2];
    }
    double size = (double)XSIZE;
    double commit = s2 / size;
    double fit = s3 / (double)NROWS;
    double mean = s0 / size;
    double var = s1 / size - mean * mean;
    if (var < 0.0) var = 0.0;
    out[SCAL_OFF + 0] = (float)commit;
    out[SCAL_OFF + 1] = (float)fit;
    out[SCAL_OFF + 2] = (float)sqrt(var);
  }
}

extern "C" void kernel_launch(void* const* d_in, const int* in_sizes, int n_in,
                              void* d_out, int out_size, void* d_ws, size_t ws_size,
                              hipStream_t stream) {
  const float* x = (const float*)d_in[0];
  const float* kg = (const float*)d_in[1];
  float* out = (float*)d_out;
  float* k2   = (float*)((char*)d_ws + WS_K2_OFF);
  int* cnt    = (int*)((char*)d_ws + WS_CNT_OFF);
  int* flags  = (int*)((char*)d_ws + WS_FLAG_OFF);
  u64* slots  = (u64*)((char*)d_ws + WS_SLOT_OFF);
  float* part = (float*)((char*)d_ws + WS_PART_OFF);
  char* kfrag = (char*)d_ws + WS_KF_OFF;
  float* kT   = (ws_size >= WS_KT_END) ? (float*)((char*)d_ws + WS_KT_OFF) : nullptr;

  hipLaunchKernelGGL(prep_kernel, dim3(KBINS / 16), dim3(256), 0, stream,
                     kg, k2, kfrag, kT, cnt, slots);
  hipLaunchKernelGGL(vq_mfma, dim3(NBLK), dim3(512), 0, stream,
                     x, kg, k2, kfrag, out, part, cnt, flags);
  hipLaunchKernelGGL(recheck_scan, dim3(2048), dim3(256), 0, stream,
                     x, kg, kT, k2, cnt, flags, slots);
  hipLaunchKernelGGL(recheck_write, dim3(256), dim3(WDIM), 0, stream,
                     kg, cnt, flags, slots, out);
  hipLaunchKernelGGL(finalize_kernel, dim3(1), dim3(256), 0, stream, part, out);
}